// Round 5
// baseline (585.557 us; speedup 1.0000x reference)
//
#include <hip/hip_runtime.h>
#include <math.h>

// SparseEdgeEmbeddingV3: out[1, N, N, 16] fp32, N=3072.
// keep(i,j) = exp(-d2/18) >= 0.9 && d2 > 0 && i != j   (sig_max = 3.0)
// out[i,j,c] = keep ? exp(-d2 / (2*sigma_c^2)) : 0
//
// R5 restructure: persistent stripes. R4 showed nt-vs-plain stores neutral;
// remaining theory is short-lived waves (1 store each, gated on a fresh load
// chain + dispatch rate) starve the store pipe. Now: 1536 blocks (6/CU, all
// co-resident), each thread holds (j, c4) fixed in registers and loops over
// 96 rows i. Per-thread constants (j-coords, sqj, sigma quad, rcp's) load
// once; per-iteration = 3 wave-uniform scalar coord loads + ~15 VALU + one
// contiguous 1 KB wave-store. unroll 4 pipelines stores.
//
// KEEP decision numerics bit-identical to R1/R3/R4-passing kernels
// (matches numpy boundary behavior on this fixed input — do not touch):
//   sq = (x*x + y*y) + z*z  (rn, no fma)
//   dot = fma(z,z, fma(y,y, x*x))
//   d2 = max((sqi+sqj) - 2*dot, 0)
//   d2<=1.8 keep, d2>2.0 drop, band decided by f64 exp(fp32(-d2/18)) >= 0.9
// Kept VALUES only need |err| << 0.02 -> native rcp + __expf.

constexpr int N_PTS = 3072;
constexpr int ROWS_PER_STRIPE = 96;                     // rows per block
constexpr int STRIPES = N_PTS / ROWS_PER_STRIPE;        // 32

__global__ __launch_bounds__(256) void sparse_edge_kernel(
    const float* __restrict__ coord,   // [N,3]
    const float* __restrict__ sigma,   // [16]
    float* __restrict__ out)           // [N,N,16]
{
    const int j  = (blockIdx.x << 6) + (threadIdx.x >> 2);  // 64 j per block
    const int c4 = threadIdx.x & 3;
    const int i_base = blockIdx.y * ROWS_PER_STRIPE;

    // ---- per-thread loop invariants (registers) ----
    const float xj = coord[3 * j + 0], yj = coord[3 * j + 1], zj = coord[3 * j + 2];
    const float sqj = __fadd_rn(__fadd_rn(__fmul_rn(xj, xj), __fmul_rn(yj, yj)),
                                __fmul_rn(zj, zj));

    const float4 s = reinterpret_cast<const float4*>(sigma)[c4];
    const float i0 = __builtin_amdgcn_rcpf(2.0f * s.x * s.x);
    const float i1 = __builtin_amdgcn_rcpf(2.0f * s.y * s.y);
    const float i2 = __builtin_amdgcn_rcpf(2.0f * s.z * s.z);
    const float i3 = __builtin_amdgcn_rcpf(2.0f * s.w * s.w);

    const float smax = sigma[15];                              // 3.0
    const float den  = __fmul_rn(__fmul_rn(2.0f, smax), smax); // 18.0 exact

    // float4 slot for (i_base, j, c4); row stride = N*16 floats = N*4 slots.
    float4* outp = reinterpret_cast<float4*>(out)
                 + (size_t)i_base * (N_PTS * 4)
                 + ((size_t)blockIdx.x << 8) + threadIdx.x;

    #pragma unroll 4
    for (int r = 0; r < ROWS_PER_STRIPE; ++r) {
        const int i = i_base + r;
        // wave-uniform address -> scalar loads, L1/L2 resident (36 KB total)
        const float xi = coord[3 * i + 0], yi = coord[3 * i + 1], zi = coord[3 * i + 2];

        // --- keep decision: EXACT R1 numerics ---
        float sqi = __fadd_rn(__fadd_rn(__fmul_rn(xi, xi), __fmul_rn(yi, yi)),
                              __fmul_rn(zi, zi));
        float dot = __fmul_rn(xi, xj);
        dot = __builtin_fmaf(yi, yj, dot);
        dot = __builtin_fmaf(zi, zj, dot);
        float d2 = __fsub_rn(__fadd_rn(sqi, sqj), __fmul_rn(2.0f, dot));
        d2 = fmaxf(d2, 0.0f);

        bool keep = (i != j) && (d2 > 0.0f) && !(d2 > 2.0f);
        if (keep && d2 > 1.8f) {
            // Rare band (~0.4% of pairs): numpy-matching arithmetic.
            float qf = __fdiv_rn(-d2, den);                    // fp32 rn
            keep = (exp((double)qf) >= 0.9);
        }

        float4 v = make_float4(0.0f, 0.0f, 0.0f, 0.0f);
        if (keep) {
            v.x = __expf(-d2 * i0);
            v.y = __expf(-d2 * i1);
            v.z = __expf(-d2 * i2);
            v.w = __expf(-d2 * i3);
        }

        outp[(size_t)r * (N_PTS * 4)] = v;
    }
}

extern "C" void kernel_launch(void* const* d_in, const int* in_sizes, int n_in,
                              void* d_out, int out_size, void* d_ws, size_t ws_size,
                              hipStream_t stream) {
    const float* coord = (const float*)d_in[0];   // [3072, 3] fp32
    const float* sigma = (const float*)d_in[1];   // [16] fp32
    float* out = (float*)d_out;                   // [1, 3072, 3072, 16] fp32

    dim3 grid(N_PTS / 64, STRIPES);   // (48, 32) = 1536 blocks, 6/CU
    dim3 block(256);
    hipLaunchKernelGGL(sparse_edge_kernel, grid, block, 0, stream,
                       coord, sigma, out);
}